// Round 10
// baseline (1204.682 us; speedup 1.0000x reference)
//
#include <hip/hip_runtime.h>

// Residual VQ forward, MFMA candidates + R3-replica exact selection. R18:
//  - Occupancy finally attacked at the true limiter: REGISTERS. R17 showed
//    VGPR_Count excludes AGPRs -> acc[8][4]=128 AGPR + 124 VGPR ~ 252/wave
//    capped ALL 256^2 variants at 2 waves/SIMD (21% occ) regardless of LDS.
//  - k_gemm_topk: 256x128 tile, 8 waves (4Mx2N), each 64x64 out ->
//    acc[4][4]=64 AGPR + ~65 VGPR ~ 128/wave -> 4 waves/SIMD possible.
//    3-buffer counted-vmcnt K-loop (R12-proven ledger, 3 gl2lds/wave/iter ->
//    vmcnt(3)). LDS 74304 (A 3x16K + B 3x8K, scb[64][132] aliases, c2s skew)
//    -> 2 blocks/CU = 16 waves. Grid 1024 blocks, XCD pinning adapted.
//  - epilogue: same validated quarter/scan/xor-merge discipline; 8 parts x
//    16 contiguous cols (merge xor{1,2,4}); scb stride 132 (R11 bank math),
//    read conflicts 8-way -> 4-way.
// Scores BIT-IDENTICAL (ascending-k MFMA chain on identical operands).
// selupd UNTOUCHED (attribution). R11: fused init, b128 epilogue, setprio.
// R10: selupd coalesced staging. R9: XCD swizzle (FETCH ideal).
// d_out flat: [quantized (B,T,D) | indices (B,T,Q) as float | loss scalar]
// Selection arithmetic (validated R3/R5/R6/R7, bit-exact vs reference):
//   sb = c2 - 2*dot_bf16 candidates (top-4 per 128-code block);
//   exact rescore = ascending 512-step fmaf chain, s = fl(fl(r2-2d)+c2),
//   contract off, lowest-index tie-break; r2/c2 numpy-pairwise order.

constexpr int DIM   = 512;
constexpr int KCB   = 2048;
constexpr int NQ    = 8;
constexpr int NTOK  = 8 * 2048;       // 16384
constexpr int QELEM = NTOK * DIM;     // 8388608
constexpr int NBLKC = KCB / 128;      // 16 col tiles (128 wide)
constexpr float WINDOW = 1e-3f;       // worst-case bf16 score err ~4.5e-4

using short8  = __attribute__((ext_vector_type(8))) short;
using float4v = __attribute__((ext_vector_type(4))) float;

__device__ __forceinline__ unsigned short f2bf(float f) {
    unsigned u = __float_as_uint(f);
    return (unsigned short)((u + 0x7FFFu + ((u >> 16) & 1u)) >> 16);   // RNE
}

__device__ __forceinline__ void gl2lds16(const void* g, void* l) {
    __builtin_amdgcn_global_load_lds(
        (__attribute__((address_space(1))) void*)g,
        (__attribute__((address_space(3))) void*)l, 16, 0, 0);
}

struct Top4 { float s[4]; int i[4]; };
__device__ __forceinline__ void t4_init(Top4& t) {
#pragma unroll
    for (int j = 0; j < 4; ++j) { t.s[j] = 3.0e38f; t.i[j] = 0x7FFFFFFF; }
}
__device__ __forceinline__ void t4_ins(Top4& t, float s, int idx) {
    if (s < t.s[3]) {
        if (s < t.s[2]) { t.s[3] = t.s[2]; t.i[3] = t.i[2];
            if (s < t.s[1]) { t.s[2] = t.s[1]; t.i[2] = t.i[1];
                if (s < t.s[0]) { t.s[1] = t.s[0]; t.i[1] = t.i[0]; t.s[0] = s; t.i[0] = idx; }
                else            { t.s[1] = s; t.i[1] = idx; }
            } else { t.s[2] = s; t.i[2] = idx; }
        } else { t.s[3] = s; t.i[3] = idx; }
    }
}

// Fused init: blocks [0,4096) handle x rows (copy R, cast Rb, np-pairwise r2);
// blocks [4096,8192) handle codebook rows (cast Cbb, np-pairwise c2).
__global__ __launch_bounds__(256) void k_initnorm(
        const float* __restrict__ x, const float* __restrict__ cbs,
        float4* __restrict__ R, ushort4* __restrict__ Rb, ushort4* __restrict__ Cbb,
        float* __restrict__ r2, float* __restrict__ c2)
{
#pragma clang fp contract(off)
    __shared__ float buf[4][DIM];
    __shared__ float accs[4][32];
    const int w = threadIdx.x >> 6, lane = threadIdx.x & 63;
    const bool isX = blockIdx.x < (NTOK / 4);
    const int row = (isX ? blockIdx.x : blockIdx.x - NTOK / 4) * 4 + w;

    const float* src = isX ? x : cbs;
    const float4* a4 = reinterpret_cast<const float4*>(src + (size_t)row * DIM);
    float4 v0 = a4[lane], v1 = a4[lane + 64];

    ushort4 b0 = make_ushort4(f2bf(v0.x), f2bf(v0.y), f2bf(v0.z), f2bf(v0.w));
    ushort4 b1 = make_ushort4(f2bf(v1.x), f2bf(v1.y), f2bf(v1.z), f2bf(v1.w));
    if (isX) {
        R [(size_t)row * 128 + lane]      = v0;
        R [(size_t)row * 128 + lane + 64] = v1;
        Rb[(size_t)row * 128 + lane]      = b0;
        Rb[(size_t)row * 128 + lane + 64] = b1;
    } else {
        Cbb[(size_t)row * 128 + lane]      = b0;
        Cbb[(size_t)row * 128 + lane + 64] = b1;
    }

    float4* b4 = reinterpret_cast<float4*>(buf[w]);
    b4[lane]      = v0;
    b4[lane + 64] = v1;
    __syncthreads();
    if (lane < 32) {
        int blk = lane >> 3, j = lane & 7;
        const float* p = buf[w] + blk * 128 + j;
        float x0 = p[0];
        float acc = x0 * x0;
#pragma unroll
        for (int m = 1; m < 16; ++m) { float xx = p[8 * m]; acc = acc + xx * xx; }
        accs[w][lane] = acc;
    }
    __syncthreads();
    if (lane == 0) {
        float B[4];
#pragma unroll
        for (int blk = 0; blk < 4; ++blk) {
            const float* r = &accs[w][blk * 8];
            B[blk] = ((r[0] + r[1]) + (r[2] + r[3])) + ((r[4] + r[5]) + (r[6] + r[7]));
        }
        float out = (B[0] + B[1]) + (B[2] + B[3]);
        if (isX) r2[row] = out; else c2[row] = out;
    }
}

// 256x128 tile bf16 MFMA GEMM (A.B^T) + per-row top-4 over the 128 cols.
// 8 waves (wr=wid>>1 in 0..3 rows, wc=wid&1 in 0..1 cols), each 64x64 out
// -> acc[4][4] = 64 AGPR/wave. 3-buffer counted-vmcnt(3) K-loop.
__global__ __launch_bounds__(512, 2) void k_gemm_topk(
        const unsigned short* __restrict__ Rb, const unsigned short* __restrict__ Cbb,
        const float* __restrict__ c2, float* __restrict__ candS, int* __restrict__ candI)
{
    // As: [0,49152) = 3 x 16KB (16 units of 1KB: unit g = rows g*16..+15,
    // lane*16B linear). Bs: [49152,73728) = 3 x 8KB (8 units).
    // scb fp32 [64][132] at 0 (33792B) ALIASES staging (dead post-K-loop).
    // c2s skewed (140 fl) at 73728. Total 74304 -> 2 blocks/CU target.
    __shared__ __align__(16) char smem[74304];
    unsigned short* As = (unsigned short*)smem;
    unsigned short* Bs = (unsigned short*)(smem + 49152);
    float*  scb = (float*)smem;
    float*  c2s = (float*)(smem + 73728);

    const int tid  = threadIdx.x;
    const int wid  = tid >> 6, lane = tid & 63;
    const int quad = lane >> 4, l16 = lane & 15;
    const int wr = wid >> 1, wc = wid & 1;

    // XCD pinning: L%8 = HW XCD round-robin; each XCD owns 8 row-panels,
    // col-tile nb iterates fastest. Bijective on [0,1024); nwg%8==0.
    const int L    = blockIdx.y * NBLKC + blockIdx.x;
    const int slot = L >> 3;                      // 0..127
    const int mb   = (L & 7) * 8 + (slot >> 4);   // 0..63 row panel (256 rows)
    const int nb   = slot & 15;                   // 0..15 col tile (128 wide)

    const int tok0 = mb * 256, n0 = nb * 128;

    // skewed c2s: float col c stored at c + 4*(c>>5)
    if (tid < 128) c2s[tid + 4 * (tid >> 5)] = c2[n0 + tid];

    float4v acc[4][4];
    float4v zero = {0.f, 0.f, 0.f, 0.f};
#pragma unroll
    for (int mi = 0; mi < 4; ++mi)
#pragma unroll
        for (int nj = 0; nj < 4; ++nj) acc[mi][nj] = zero;

    // stage K-tile kb (32 wide) into buffer b: wave wid stages A units
    // {wid, wid+8} and B unit {wid} -> exactly 3 gl2lds/wave/iter.
    // Unit g: lane (quad,l16) loads row g*16+l16, k = kb+quad*8
    // -> LDS unit base g*512 shorts (+lane*16B HW).
    auto stage = [&](int b, int kb) {
        unsigned short* Ad = As + b * 8192;
        unsigned short* Bd = Bs + b * 4096;
#pragma unroll
        for (int c = 0; c < 2; ++c) {
            int g = wid + c * 8;
            gl2lds16(&Rb[(size_t)(tok0 + g * 16 + l16) * DIM + kb + quad * 8],
                     Ad + (size_t)g * 512);
        }
        gl2lds16(&Cbb[(size_t)(n0 + wid * 16 + l16) * DIM + kb + quad * 8],
                 Bd + (size_t)wid * 512);
    };

    auto compute = [&](int b) {
        const unsigned short* Ac = As + b * 8192;
        const unsigned short* Bc = Bs + b * 4096;
        short8 af[4], bf[4];
#pragma unroll
        for (int mi = 0; mi < 4; ++mi)
            af[mi] = *(const short8*)(Ac + (size_t)(wr * 4 + mi) * 512 + lane * 8);
#pragma unroll
        for (int nj = 0; nj < 4; ++nj)
            bf[nj] = *(const short8*)(Bc + (size_t)(wc * 4 + nj) * 512 + lane * 8);
        __builtin_amdgcn_s_setprio(1);                 // T5
#pragma unroll
        for (int mi = 0; mi < 4; ++mi)
#pragma unroll
            for (int nj = 0; nj < 4; ++nj)
                acc[mi][nj] = __builtin_amdgcn_mfma_f32_16x16x32_bf16(
                    af[mi], bf[nj], acc[mi][nj], 0, 0, 0);
        __builtin_amdgcn_s_setprio(0);
    };

    // K-loop (R12-proven counted ledger, 3 loads/wave/iter): at iter top the
    // wave has tiles it (3 loads, oldest) and it+1 (3) in flight; vmcnt(3)
    // => tile it landed; barrier => for all waves; stage(it+2) reuses the
    // buffer computed at it-1 (all waves past barrier => done reading it).
    stage(0, 0);
    stage(1, 32);
    int cur = 0, pf = 2;
    for (int it = 0; it < 16; ++it) {
        if (it < 15) asm volatile("s_waitcnt vmcnt(3)" ::: "memory");
        else         asm volatile("s_waitcnt vmcnt(0)" ::: "memory");
        __builtin_amdgcn_s_barrier();
        __builtin_amdgcn_sched_barrier(0);
        if (it < 14) stage(pf, (it + 2) * 32);
        compute(cur);
        cur = (cur == 2) ? 0 : cur + 1;
        pf  = (pf  == 2) ? 0 : pf  + 1;
    }

    // epilogue: 4 row-quarters of 64 rows x 128 cols via scb stride 132
    // (R11-validated bank math: writes 2 lanes/bank). Readers: thread
    // (row_=tid>>3, pp=tid&7) owns 16 CONTIGUOUS cols pp*16.. ; ascending
    // scan + xor{1,2,4} merge over the 8 parts (validated discipline family).
    const int row_ = tid >> 3, pp = tid & 7;
    float4 c2r[4];
#pragma unroll
    for (int j = 0; j < 4; ++j)
        c2r[j] = *(const float4*)(c2s + pp * 16 + 4 * (pp >> 1) + 4 * j);  // skew

#pragma unroll
    for (int qr = 0; qr < 4; ++qr) {
        __syncthreads();
        if (wr == qr) {
#pragma unroll
            for (int mi = 0; mi < 4; ++mi)
#pragma unroll
                for (int nj = 0; nj < 4; ++nj) {
                    int r0 = mi * 16 + quad * 4;
                    int cc = wc * 64 + nj * 16 + l16;
#pragma unroll
                    for (int e = 0; e < 4; ++e)
                        scb[(r0 + e) * 132 + cc] = acc[mi][nj][e];
                }
        }
        __syncthreads();
        Top4 t; t4_init(t);
#pragma unroll
        for (int j = 0; j < 4; ++j) {
            float4 sv = *(const float4*)(scb + row_ * 132 + pp * 16 + 4 * j);
            float4 cv = c2r[j];
            int c0 = n0 + pp * 16 + 4 * j;
            t4_ins(t, cv.x - 2.0f * sv.x, c0 + 0);
            t4_ins(t, cv.y - 2.0f * sv.y, c0 + 1);
            t4_ins(t, cv.z - 2.0f * sv.z, c0 + 2);
            t4_ins(t, cv.w - 2.0f * sv.w, c0 + 3);
        }
        // merge the 8 parts of this row (8 adjacent lanes of one wave)
#pragma unroll
        for (int k = 1; k <= 4; k <<= 1) {
            float os[4]; int oi[4];
#pragma unroll
            for (int j = 0; j < 4; ++j) {
                os[j] = __shfl_xor(t.s[j], k, 64);
                oi[j] = __shfl_xor(t.i[j], k, 64);
            }
#pragma unroll
            for (int j = 0; j < 4; ++j) t4_ins(t, os[j], oi[j]);
        }
        if (pp == 0) {
            int token = tok0 + qr * 64 + row_;
            size_t base = (size_t)token * 64 + (size_t)nb * 4;
#pragma unroll
            for (int j = 0; j < 4; ++j) { candS[base + j] = t.s[j]; candI[base + j] = t.i[j]; }
        }
    }
}

// Fused: select winner (R3-replica exact rescore of in-window candidates),
// update residual, recast bf16, np-ordered r2 for next level, loss partial.
__global__ __launch_bounds__(256) void k_selupd(
        const float* __restrict__ candS, const int* __restrict__ candI,
        float* __restrict__ R, const float* __restrict__ cbf,
        float* __restrict__ r2, const float* __restrict__ c2,
        float* __restrict__ idx_out, float* __restrict__ partial,
        ushort4* __restrict__ Rb, const float4* __restrict__ x, int level)
{
#pragma clang fp contract(off)
    __shared__ float buf[4][DIM];
    __shared__ float accs[4][32];
    __shared__ float shl[4];
    const int w = threadIdx.x >> 6, lane = threadIdx.x & 63;
    const int t = blockIdx.x * 4 + w;
    const bool last = (level == NQ - 1);

    // ---- stage R row (coalesced) into regs + per-wave LDS copy ----
    float4* r4 = reinterpret_cast<float4*>(R + (size_t)t * DIM);
    float4* b4 = reinterpret_cast<float4*>(buf[w]);
    float4 rr[2];
    rr[0] = r4[lane];      rr[1] = r4[lane + 64];
    b4[lane] = rr[0];      b4[lane + 64] = rr[1];

    // ---- select ----
    float sb = candS[(size_t)t * 64 + lane];
    int   ci = candI[(size_t)t * 64 + lane];
    float mn = sb;
#pragma unroll
    for (int off = 32; off; off >>= 1) mn = fminf(mn, __shfl_xor(mn, off, 64));
    unsigned long long mask = __ballot(sb <= mn + WINDOW);
    int ncand = __popcll(mask);
    int winner;
    if (ncand == 1) {
        winner = __shfl(ci, __ffsll(mask) - 1, 64);
    } else {
        int src = 0;
        if (lane < ncand) {
            unsigned long long mm = mask;
            for (int z = 0; z < lane; ++z) mm &= mm - 1;
            src = __ffsll(mm) - 1;
        }
        int cidx = __shfl(ci, src, 64);
        float s = 3.0e38f;
        int   si = 0x7FFFFFFF;
        if (lane < ncand) {
            const float4* cp4 = reinterpret_cast<const float4*>(cbf + (size_t)cidx * DIM);
            const float4* rp4 = reinterpret_cast<const float4*>(buf[w]);  // broadcast
            float d = 0.f;
#pragma unroll 4
            for (int j = 0; j < DIM / 4; ++j) {
                float4 cv = cp4[j];
                float4 rv = rp4[j];
                d = fmaf(rv.x, cv.x, d);
                d = fmaf(rv.y, cv.y, d);
                d = fmaf(rv.z, cv.z, d);
                d = fmaf(rv.w, cv.w, d);
            }
            float td = 2.0f * d;
            float a  = r2[t] - td;
            s  = a + c2[cidx];
            si = cidx;
        }
#pragma unroll
        for (int off = 32; off; off >>= 1) {
            float ov = __shfl_xor(s, off, 64);
            int   oi = __shfl_xor(si, off, 64);
            if (ov < s || (ov == s && oi < si)) { s = ov; si = oi; }
        }
        winner = si;
    }
    if (lane == 0) idx_out[(size_t)t * NQ + level] = (float)winner;

    // ---- update (reuses staged rr; values identical to re-reading R) ----
    const float4* c4 = reinterpret_cast<const float4*>(cbf + (size_t)winner * DIM);
    float ls = 0.f;
#pragma unroll
    for (int i = 0; i < 2; ++i) {
        int d = lane + 64 * i;
        float4 rv = rr[i], cv = c4[d];
        rv.x -= cv.x; rv.y -= cv.y; rv.z -= cv.z; rv.w -= cv.w;
        ls = ls + rv.x * rv.x; ls = ls + rv.y * rv.y;
        ls = ls + rv.z * rv.z; ls = ls + rv.w * rv.w;
        if (!last) {
            r4[d] = rv;
            b4[d] = rv;
            Rb[(size_t)t * 128 + d] = make_ushort4(f2bf(rv.x), f2bf(rv.y),
                                                   f2bf(rv.z), f2bf(rv.w));
        } else {
            float4 xv = x[(size_t)t * 128 + d];
            xv.x -= rv.x; xv.y -= rv.y; xv.z -= rv.z; xv.w -= rv.w;
            r4[d] = xv;                       // quantized = x - r_final (in d_out)
        }
    }

    if (!last) {
        __syncthreads();
        // np-pairwise r2 of the NEW residual (same order as k_initnorm)
        if (lane < 32) {
            int blk = lane >> 3, j = lane & 7;
            const float* p = buf[w] + blk * 128 + j;
            float x0 = p[0];
            float acc = x0 * x0;
#pragma unroll
            for (int m = 1; m < 16; ++m) { float xx = p[8 * m]; acc = acc + xx * xx; }
            accs[w][lane] = acc;
        }
        __syncthreads();
        if (lane == 0) {
            float B[4];
#pragma unroll
            for (int blk = 0; blk < 4; ++blk) {
                const float* r = &accs[w][blk * 8];
                B[blk] = ((r[0] + r[1]) + (r[2] + r[3])) + ((r[4] + r[5]) + (r[6] + r[7]));
            }
            r2[t] = (B[0] + B[1]) + (B[2] + B[3]);
        }
    }

    // ---- loss partial ----
#pragma unroll
    for (int off = 32; off; off >>= 1) ls += __shfl_down(ls, off, 64);
    if (lane == 0) shl[w] = ls;
    __syncthreads();
    if (threadIdx.x == 0) partial[blockIdx.x] = (shl[0] + shl[1]) + (shl[2] + shl[3]);
}

__global__ __launch_bounds__(256) void k_finalize_loss(const float* __restrict__ partial,
                                                       float* __restrict__ loss_out)
{
    double s = 0.0;
    for (int i = threadIdx.x; i < NQ * (NTOK / 4); i += 256) s += (double)partial[i];
#pragma unroll
    for (int off = 32; off; off >>= 1) s += __shfl_down(s, off, 64);
    __shared__ double sh[4];
    if ((threadIdx.x & 63) == 0) sh[threadIdx.x >> 6] = s;
    __syncthreads();
    if (threadIdx.x == 0) {
        double tot = (sh[0] + sh[1]) + (sh[2] + sh[3]);
        loss_out[0] = (float)(tot * 1.25 / ((double)NQ * (double)QELEM));
    }
}

extern "C" void kernel_launch(void* const* d_in, const int* in_sizes, int n_in,
                              void* d_out, int out_size, void* d_ws, size_t ws_size,
                              hipStream_t stream)
{
    const float* x   = (const float*)d_in[0];
    const float* cbs = (const float*)d_in[1];

    float* qout     = (float*)d_out;
    float* idx_out  = qout + QELEM;
    float* loss_out = idx_out + (size_t)NTOK * NQ;
    float* R        = qout;                 // residual lives in d_out (validated R5)

    char* ws = (char*)d_ws;
    size_t off = 0;
    unsigned short* Rb   = (unsigned short*)(ws + off); off += (size_t)QELEM * 2;  // 16MB
    unsigned short* Cbb  = (unsigned short*)(ws + off); off += (size_t)QELEM * 2;  // 16MB
    float*          c2   = (float*)(ws + off);          off += (size_t)NQ * KCB * 4;
    float*          r2   = (float*)(ws + off);          off += (size_t)NTOK * 4;
    float*          part = (float*)(ws + off);          off += (size_t)NQ * (NTOK / 4) * 4;
    float*          candS= (float*)(ws + off);          off += (size_t)NTOK * 64 * 4; // 4MB
    int*            candI= (int*)(ws + off);            off += (size_t)NTOK * 64 * 4; // 4MB

    // fused init: x rows (R copy, Rb cast, r2) + cb rows (Cbb cast, c2)
    k_initnorm<<<NTOK / 4 + NQ * KCB / 4, 256, 0, stream>>>(
        x, cbs, (float4*)R, (ushort4*)Rb, (ushort4*)Cbb, r2, c2);

    for (int q = 0; q < NQ; ++q) {
        const float*          cbq  = cbs + (size_t)q * KCB * DIM;
        const unsigned short* cbbq = Cbb + (size_t)q * KCB * DIM;
        const float*          c2q  = c2 + (size_t)q * KCB;
        dim3 g(NBLKC, NTOK / 256);
        k_gemm_topk<<<g, 512, 0, stream>>>(Rb, cbbq, c2q, candS, candI);
        k_selupd<<<NTOK / 4, 256, 0, stream>>>(candS, candI, R, cbq, r2, c2q,
                                               idx_out, part + (size_t)q * (NTOK / 4),
                                               (ushort4*)Rb, (const float4*)x, q);
    }

    k_finalize_loss<<<1, 256, 0, stream>>>(part, loss_out);
}

// Round 11
// 1008.203 us; speedup vs baseline: 1.1949x; 1.1949x over previous
//
#include <hip/hip_runtime.h>

// Residual VQ forward, MFMA candidates + R3-replica exact selection. R19:
//  - k_gemm_topk: REVERT to R12 verbatim (best measured, 76.1us) + c2s skew
//    (R14/R15-proven: conflicts 917K->524K). R13-R18 established: with a
//    64+-AGPR accumulator the kernel is register-quantization-locked at
//    2-3 waves/SIMD and every structure lands 76-104us -> R12 is the floor.
//  - k_selupd: (a) speculative prefetch of the bf16-argmin candidate's row
//    (provably the winner when ncand==1; most-likely winner otherwise) --
//    issued before the rescore chain so the 2KB broadcast load hides under
//    it; consumed only if winner==pred, else reload (same floats, bit-exact).
//    (b) intra-wave __syncthreads in the r2 section replaced by lgkmcnt(0)
//    (+sched_barrier, rule#18): buf/accs are per-wave; removes 2 cross-wave
//    convergence stalls. Cross-wave loss barrier kept.
// Scores BIT-IDENTICAL; selection discipline unchanged.
// R12: 256^2 geometry, 3-buffer vmcnt(4) ledger. R11: fused init, b128
// epilogue, setprio. R10: selupd coalesced staging. R9: XCD swizzle.
// d_out flat: [quantized (B,T,D) | indices (B,T,Q) as float | loss scalar]
// Selection arithmetic (validated R3/R5/R6/R7, bit-exact vs reference):
//   sb = c2 - 2*dot_bf16 candidates (top-4 per 128-code block);
//   exact rescore = ascending 512-step fmaf chain, s = fl(fl(r2-2d)+c2),
//   contract off, lowest-index tie-break; r2/c2 numpy-pairwise order.

constexpr int DIM   = 512;
constexpr int KCB   = 2048;
constexpr int NQ    = 8;
constexpr int NTOK  = 8 * 2048;       // 16384
constexpr int QELEM = NTOK * DIM;     // 8388608
constexpr int NBLK2 = KCB / 256;      // 8 column tiles (256 wide)
constexpr float WINDOW = 1e-3f;       // worst-case bf16 score err ~4.5e-4

using short8  = __attribute__((ext_vector_type(8))) short;
using float4v = __attribute__((ext_vector_type(4))) float;

__device__ __forceinline__ unsigned short f2bf(float f) {
    unsigned u = __float_as_uint(f);
    return (unsigned short)((u + 0x7FFFu + ((u >> 16) & 1u)) >> 16);   // RNE
}

__device__ __forceinline__ void gl2lds16(const void* g, void* l) {
    __builtin_amdgcn_global_load_lds(
        (__attribute__((address_space(1))) void*)g,
        (__attribute__((address_space(3))) void*)l, 16, 0, 0);
}

struct Top4 { float s[4]; int i[4]; };
__device__ __forceinline__ void t4_init(Top4& t) {
#pragma unroll
    for (int j = 0; j < 4; ++j) { t.s[j] = 3.0e38f; t.i[j] = 0x7FFFFFFF; }
}
__device__ __forceinline__ void t4_ins(Top4& t, float s, int idx) {
    if (s < t.s[3]) {
        if (s < t.s[2]) { t.s[3] = t.s[2]; t.i[3] = t.i[2];
            if (s < t.s[1]) { t.s[2] = t.s[1]; t.i[2] = t.i[1];
                if (s < t.s[0]) { t.s[1] = t.s[0]; t.i[1] = t.i[0]; t.s[0] = s; t.i[0] = idx; }
                else            { t.s[1] = s; t.i[1] = idx; }
            } else { t.s[2] = s; t.i[2] = idx; }
        } else { t.s[3] = s; t.i[3] = idx; }
    }
}

// Fused init: blocks [0,4096) handle x rows (copy R, cast Rb, np-pairwise r2);
// blocks [4096,8192) handle codebook rows (cast Cbb, np-pairwise c2).
__global__ __launch_bounds__(256) void k_initnorm(
        const float* __restrict__ x, const float* __restrict__ cbs,
        float4* __restrict__ R, ushort4* __restrict__ Rb, ushort4* __restrict__ Cbb,
        float* __restrict__ r2, float* __restrict__ c2)
{
#pragma clang fp contract(off)
    __shared__ float buf[4][DIM];
    __shared__ float accs[4][32];
    const int w = threadIdx.x >> 6, lane = threadIdx.x & 63;
    const bool isX = blockIdx.x < (NTOK / 4);
    const int row = (isX ? blockIdx.x : blockIdx.x - NTOK / 4) * 4 + w;

    const float* src = isX ? x : cbs;
    const float4* a4 = reinterpret_cast<const float4*>(src + (size_t)row * DIM);
    float4 v0 = a4[lane], v1 = a4[lane + 64];

    ushort4 b0 = make_ushort4(f2bf(v0.x), f2bf(v0.y), f2bf(v0.z), f2bf(v0.w));
    ushort4 b1 = make_ushort4(f2bf(v1.x), f2bf(v1.y), f2bf(v1.z), f2bf(v1.w));
    if (isX) {
        R [(size_t)row * 128 + lane]      = v0;
        R [(size_t)row * 128 + lane + 64] = v1;
        Rb[(size_t)row * 128 + lane]      = b0;
        Rb[(size_t)row * 128 + lane + 64] = b1;
    } else {
        Cbb[(size_t)row * 128 + lane]      = b0;
        Cbb[(size_t)row * 128 + lane + 64] = b1;
    }

    float4* b4 = reinterpret_cast<float4*>(buf[w]);
    b4[lane]      = v0;
    b4[lane + 64] = v1;
    __syncthreads();
    if (lane < 32) {
        int blk = lane >> 3, j = lane & 7;
        const float* p = buf[w] + blk * 128 + j;
        float x0 = p[0];
        float acc = x0 * x0;
#pragma unroll
        for (int m = 1; m < 16; ++m) { float xx = p[8 * m]; acc = acc + xx * xx; }
        accs[w][lane] = acc;
    }
    __syncthreads();
    if (lane == 0) {
        float B[4];
#pragma unroll
        for (int blk = 0; blk < 4; ++blk) {
            const float* r = &accs[w][blk * 8];
            B[blk] = ((r[0] + r[1]) + (r[2] + r[3])) + ((r[4] + r[5]) + (r[6] + r[7]));
        }
        float out = (B[0] + B[1]) + (B[2] + B[3]);
        if (isX) r2[row] = out; else c2[row] = out;
    }
}

// 256x256 tile bf16 MFMA GEMM (A.B^T) + per-row top-4 per 128-col block.
// R12 verbatim (best measured) + skewed c2s. 8 waves (2Mx4N), 128x64 each.
__global__ __launch_bounds__(512, 2) void k_gemm_topk(
        const unsigned short* __restrict__ Rb, const unsigned short* __restrict__ Cbb,
        const float* __restrict__ c2, float* __restrict__ candS, int* __restrict__ candI)
{
    // A bufs: [0,49152) = A0|A1|A2 (16KB each). B bufs: [49152,98304).
    // c2s skewed (288 fl) at 98304. scb fp32 [64][260] aliases staging
    // post-K-loop (66560B). Total 99456 -> 1 block/CU, 8 waves.
    __shared__ __align__(16) char smem[99456];
    unsigned short* As = (unsigned short*)smem;
    unsigned short* Bs = (unsigned short*)(smem + 49152);
    float*  scb = (float*)smem;
    float*  c2s = (float*)(smem + 98304);

    const int tid  = threadIdx.x;
    const int wid  = tid >> 6, lane = tid & 63;
    const int quad = lane >> 4, l16 = lane & 15;
    const int wr = wid >> 2, wc = wid & 3;

    // XCD pinning: L%8 = HW XCD round-robin; each XCD owns 8 row-panels,
    // col-tile nb2 iterates fastest. Bijective on [0,512).
    const int L    = blockIdx.y * NBLK2 + blockIdx.x;
    const int slot = L >> 3;
    const int mb   = (L & 7) * 8 + (slot >> 3);   // 0..63 row panel
    const int nb2  = slot & 7;                    // 0..7 col tile (256 wide)

    const int tok0 = mb * 256, n0 = nb2 * 256;

    // skewed c2s: float col c stored at c + 4*(c>>5) (kills the bank-aligned
    // c2s chunk reads that were 917K->524K of conflict cycles)
    if (tid < 256) c2s[tid + 4 * (tid >> 5)] = c2[n0 + tid];

    float4v acc[8][4];
    float4v zero = {0.f, 0.f, 0.f, 0.f};
#pragma unroll
    for (int mi = 0; mi < 8; ++mi)
#pragma unroll
        for (int nj = 0; nj < 4; ++nj) acc[mi][nj] = zero;

    // stage K-tile kb into buffer b3: wave wid stages A units {wid*2,wid*2+1}
    // and B units {wid*2,wid*2+1}. Unit g: lane (quad,l16) loads row
    // g*16+l16, k-chunk quad -> LDS unit base g*1024B (+lane*16 HW).
    // Exactly 4 gl2lds per wave per stage -> vmcnt(4) ledger.
    auto stage = [&](int b3, int kb) {
        unsigned short* Ad = As + b3 * 8192;
        unsigned short* Bd = Bs + b3 * 8192;
#pragma unroll
        for (int c = 0; c < 2; ++c) {
            int g = wid * 2 + c;
            gl2lds16(&Rb[(size_t)(tok0 + g * 16 + l16) * DIM + kb + quad * 8],
                     Ad + (size_t)(g * 64) * 8);
        }
#pragma unroll
        for (int c = 0; c < 2; ++c) {
            int g = wid * 2 + c;
            gl2lds16(&Cbb[(size_t)(n0 + g * 16 + l16) * DIM + kb + quad * 8],
                     Bd + (size_t)(g * 64) * 8);
        }
    };

    auto compute = [&](int b3) {
        const unsigned short* Ac = As + b3 * 8192;
        const unsigned short* Bc = Bs + b3 * 8192;
        short8 af[8], bf[4];
#pragma unroll
        for (int mi = 0; mi < 8; ++mi)
            af[mi] = *(const short8*)(Ac + ((size_t)(wr * 8 + mi) * 64 + lane) * 8);
#pragma unroll
        for (int nj = 0; nj < 4; ++nj)
            bf[nj] = *(const short8*)(Bc + ((size_t)(wc * 4 + nj) * 64 + lane) * 8);
        __builtin_amdgcn_s_setprio(1);                 // T5
#pragma unroll
        for (int mi = 0; mi < 8; ++mi)
#pragma unroll
            for (int nj = 0; nj < 4; ++nj)
                acc[mi][nj] = __builtin_amdgcn_mfma_f32_16x16x32_bf16(
                    af[mi], bf[nj], acc[mi][nj], 0, 0, 0);
        __builtin_amdgcn_s_setprio(0);
    };

    // K-loop (R12 ledger): per iter each wave issues 4 gl2lds; vmcnt(4) =>
    // stage(it) landed (stage(it+1)'s 4 are the newest); barrier => landed
    // for ALL waves; stage(it+2) reuses the buffer read at it-1.
    stage(0, 0);
    stage(1, 32);
    for (int it = 0; it < 16; ++it) {
        if (it < 15) asm volatile("s_waitcnt vmcnt(4)" ::: "memory");
        else         asm volatile("s_waitcnt vmcnt(0)" ::: "memory");
        __builtin_amdgcn_s_barrier();
        __builtin_amdgcn_sched_barrier(0);
        if (it < 14) stage((it + 2) % 3, (it + 2) * 32);
        compute(it % 3);
    }

    // epilogue (R12 structure, validated): 4 row-quarters of 64x256 via scb
    // stride 260. Thread (row=tid>>3, pp=tid&7): block pp>>2, part pp&3 owns
    // 32 contiguous cols; ascending scan + xor(1,2) merge.
    const int row_ = tid >> 3, pp = tid & 7;
    float4 c2r[8];
#pragma unroll
    for (int j = 0; j < 8; ++j)
        c2r[j] = *(const float4*)(c2s + pp * 36 + 4 * j);   // skew: (pp*32+4j)+4*pp

#pragma unroll
    for (int qr = 0; qr < 4; ++qr) {
        __syncthreads();
        if (wr == (qr >> 1)) {
            const int mi0 = (qr & 1) * 4;
#pragma unroll
            for (int mm = 0; mm < 4; ++mm)
#pragma unroll
                for (int nj = 0; nj < 4; ++nj) {
                    int r0 = mm * 16 + quad * 4;
                    int cc = wc * 64 + nj * 16 + l16;
#pragma unroll
                    for (int e = 0; e < 4; ++e)
                        scb[(r0 + e) * 260 + cc] = acc[mi0 + mm][nj][e];
                }
        }
        __syncthreads();
        Top4 t; t4_init(t);
#pragma unroll
        for (int j = 0; j < 8; ++j) {
            float4 sv = *(const float4*)(scb + row_ * 260 + pp * 32 + 4 * j);
            float4 cv = c2r[j];
            int c0 = n0 + pp * 32 + 4 * j;
            t4_ins(t, cv.x - 2.0f * sv.x, c0 + 0);
            t4_ins(t, cv.y - 2.0f * sv.y, c0 + 1);
            t4_ins(t, cv.z - 2.0f * sv.z, c0 + 2);
            t4_ins(t, cv.w - 2.0f * sv.w, c0 + 3);
        }
        // merge the 4 parts of this (row, 128-block) via xor shuffles
#pragma unroll
        for (int k = 1; k <= 2; k <<= 1) {
            float os[4]; int oi[4];
#pragma unroll
            for (int j = 0; j < 4; ++j) {
                os[j] = __shfl_xor(t.s[j], k, 64);
                oi[j] = __shfl_xor(t.i[j], k, 64);
            }
#pragma unroll
            for (int j = 0; j < 4; ++j) t4_ins(t, os[j], oi[j]);
        }
        if ((pp & 3) == 0) {
            int token = tok0 + qr * 64 + row_;
            int nb = nb2 * 2 + (pp >> 2);
            size_t base = (size_t)token * 64 + (size_t)nb * 4;
#pragma unroll
            for (int j = 0; j < 4; ++j) { candS[base + j] = t.s[j]; candI[base + j] = t.i[j]; }
        }
    }
}

// Fused: select winner (R3-replica exact rescore of in-window candidates),
// update residual, recast bf16, np-ordered r2 for next level, loss partial.
// R19: speculative winner-row prefetch; intra-wave barriers -> lgkmcnt.
__global__ __launch_bounds__(256) void k_selupd(
        const float* __restrict__ candS, const int* __restrict__ candI,
        float* __restrict__ R, const float* __restrict__ cbf,
        float* __restrict__ r2, const float* __restrict__ c2,
        float* __restrict__ idx_out, float* __restrict__ partial,
        ushort4* __restrict__ Rb, const float4* __restrict__ x, int level)
{
#pragma clang fp contract(off)
    __shared__ float buf[4][DIM];
    __shared__ float accs[4][32];
    __shared__ float shl[4];
    const int w = threadIdx.x >> 6, lane = threadIdx.x & 63;
    const int t = blockIdx.x * 4 + w;
    const bool last = (level == NQ - 1);

    // ---- stage R row (coalesced) into regs + per-wave LDS copy ----
    float4* r4 = reinterpret_cast<float4*>(R + (size_t)t * DIM);
    float4* b4 = reinterpret_cast<float4*>(buf[w]);
    float4 rr[2];
    rr[0] = r4[lane];      rr[1] = r4[lane + 64];
    b4[lane] = rr[0];      b4[lane + 64] = rr[1];

    // ---- select ----
    float sb = candS[(size_t)t * 64 + lane];
    int   ci = candI[(size_t)t * 64 + lane];
    float mn = sb;
#pragma unroll
    for (int off = 32; off; off >>= 1) mn = fminf(mn, __shfl_xor(mn, off, 64));
    unsigned long long mask = __ballot(sb <= mn + WINDOW);

    // speculative prefetch of the most-likely winner's row: the bf16-argmin
    // candidate (provably the winner when ncand==1). Issued BEFORE the
    // rescore so the 2KB broadcast load hides under the 512-fmaf chain.
    unsigned long long mmin = __ballot(sb == mn);
    int pred = __shfl(ci, __ffsll(mmin) - 1, 64);
    const float4* p4 = reinterpret_cast<const float4*>(cbf + (size_t)pred * DIM);
    float4 pc0 = p4[lane], pc1 = p4[lane + 64];

    int ncand = __popcll(mask);
    int winner;
    if (ncand == 1) {
        winner = __shfl(ci, __ffsll(mask) - 1, 64);
    } else {
        int src = 0;
        if (lane < ncand) {
            unsigned long long mm = mask;
            for (int z = 0; z < lane; ++z) mm &= mm - 1;
            src = __ffsll(mm) - 1;
        }
        int cidx = __shfl(ci, src, 64);
        float s = 3.0e38f;
        int   si = 0x7FFFFFFF;
        if (lane < ncand) {
            const float4* cp4 = reinterpret_cast<const float4*>(cbf + (size_t)cidx * DIM);
            const float4* rp4 = reinterpret_cast<const float4*>(buf[w]);  // broadcast
            float d = 0.f;
#pragma unroll 4
            for (int j = 0; j < DIM / 4; ++j) {
                float4 cv = cp4[j];
                float4 rv = rp4[j];
                d = fmaf(rv.x, cv.x, d);
                d = fmaf(rv.y, cv.y, d);
                d = fmaf(rv.z, cv.z, d);
                d = fmaf(rv.w, cv.w, d);
            }
            float td = 2.0f * d;
            float a  = r2[t] - td;
            s  = a + c2[cidx];
            si = cidx;
        }
#pragma unroll
        for (int off = 32; off; off >>= 1) {
            float ov = __shfl_xor(s, off, 64);
            int   oi = __shfl_xor(si, off, 64);
            if (ov < s || (ov == s && oi < si)) { s = ov; si = oi; }
        }
        winner = si;
    }
    if (lane == 0) idx_out[(size_t)t * NQ + level] = (float)winner;

    // winner row: use prefetched regs when the prediction hit (same memory,
    // same floats -> bit-exact); reload only on mispredict (wave-uniform).
    float4 cv0, cv1;
    if (winner == pred) { cv0 = pc0; cv1 = pc1; }
    else {
        const float4* c4 = reinterpret_cast<const float4*>(cbf + (size_t)winner * DIM);
        cv0 = c4[lane]; cv1 = c4[lane + 64];
    }

    // ---- update (reuses staged rr; values identical to re-reading R) ----
    float ls = 0.f;
#pragma unroll
    for (int i = 0; i < 2; ++i) {
        int d = lane + 64 * i;
        float4 rv = rr[i], cv = (i == 0) ? cv0 : cv1;
        rv.x -= cv.x; rv.y -= cv.y; rv.z -= cv.z; rv.w -= cv.w;
        ls = ls + rv.x * rv.x; ls = ls + rv.y * rv.y;
        ls = ls + rv.z * rv.z; ls = ls + rv.w * rv.w;
        if (!last) {
            r4[d] = rv;
            b4[d] = rv;
            Rb[(size_t)t * 128 + d] = make_ushort4(f2bf(rv.x), f2bf(rv.y),
                                                   f2bf(rv.z), f2bf(rv.w));
        } else {
            float4 xv = x[(size_t)t * 128 + d];
            xv.x -= rv.x; xv.y -= rv.y; xv.z -= rv.z; xv.w -= rv.w;
            r4[d] = xv;                       // quantized = x - r_final (in d_out)
        }
    }

    if (!last) {
        // buf[w]/accs[w] are PER-WAVE: same-wave LDS ordering + lgkmcnt
        // suffices (no cross-wave dep) -- was __syncthreads (R19).
        asm volatile("s_waitcnt lgkmcnt(0)" ::: "memory");
        __builtin_amdgcn_sched_barrier(0);
        // np-pairwise r2 of the NEW residual (same order as k_initnorm)
        if (lane < 32) {
            int blk = lane >> 3, j = lane & 7;
            const float* p = buf[w] + blk * 128 + j;
            float x0 = p[0];
            float acc = x0 * x0;
#pragma unroll
            for (int m = 1; m < 16; ++m) { float xx = p[8 * m]; acc = acc + xx * xx; }
            accs[w][lane] = acc;
        }
        asm volatile("s_waitcnt lgkmcnt(0)" ::: "memory");
        __builtin_amdgcn_sched_barrier(0);
        if (lane == 0) {
            float B[4];
#pragma unroll
            for (int blk = 0; blk < 4; ++blk) {
                const float* r = &accs[w][blk * 8];
                B[blk] = ((r[0] + r[1]) + (r[2] + r[3])) + ((r[4] + r[5]) + (r[6] + r[7]));
            }
            r2[t] = (B[0] + B[1]) + (B[2] + B[3]);
        }
    }

    // ---- loss partial (cross-wave: real barrier kept) ----
#pragma unroll
    for (int off = 32; off; off >>= 1) ls += __shfl_down(ls, off, 64);
    if (lane == 0) shl[w] = ls;
    __syncthreads();
    if (threadIdx.x == 0) partial[blockIdx.x] = (shl[0] + shl[1]) + (shl[2] + shl[3]);
}

__global__ __launch_bounds__(256) void k_finalize_loss(const float* __restrict__ partial,
                                                       float* __restrict__ loss_out)
{
    double s = 0.0;
    for (int i = threadIdx.x; i < NQ * (NTOK / 4); i += 256) s += (double)partial[i];
#pragma unroll
    for (int off = 32; off; off >>= 1) s += __shfl_down(s, off, 64);
    __shared__ double sh[4];
    if ((threadIdx.x & 63) == 0) sh[threadIdx.x >> 6] = s;
    __syncthreads();
    if (threadIdx.x == 0) {
        double tot = (sh[0] + sh[1]) + (sh[2] + sh[3]);
        loss_out[0] = (float)(tot * 1.25 / ((double)NQ * (double)QELEM));
    }
}

extern "C" void kernel_launch(void* const* d_in, const int* in_sizes, int n_in,
                              void* d_out, int out_size, void* d_ws, size_t ws_size,
                              hipStream_t stream)
{
    const float* x   = (const float*)d_in[0];
    const float* cbs = (const float*)d_in[1];

    float* qout     = (float*)d_out;
    float* idx_out  = qout + QELEM;
    float* loss_out = idx_out + (size_t)NTOK * NQ;
    float* R        = qout;                 // residual lives in d_out (validated R5)

    char* ws = (char*)d_ws;
    size_t off = 0;
    unsigned short* Rb   = (unsigned short*)(ws + off); off += (size_t)QELEM * 2;  // 16MB
    unsigned short* Cbb  = (unsigned short*)(ws + off); off += (size_t)QELEM * 2;  // 16MB
    float*          c2   = (float*)(ws + off);          off += (size_t)NQ * KCB * 4;
    float*          r2   = (float*)(ws + off);          off += (size_t)NTOK * 4;
    float*          part = (float*)(ws + off);          off += (size_t)NQ * (NTOK / 4) * 4;
    float*          candS= (float*)(ws + off);          off += (size_t)NTOK * 64 * 4; // 4MB
    int*            candI= (int*)(ws + off);            off += (size_t)NTOK * 64 * 4; // 4MB

    // fused init: x rows (R copy, Rb cast, r2) + cb rows (Cbb cast, c2)
    k_initnorm<<<NTOK / 4 + NQ * KCB / 4, 256, 0, stream>>>(
        x, cbs, (float4*)R, (ushort4*)Rb, (ushort4*)Cbb, r2, c2);

    for (int q = 0; q < NQ; ++q) {
        const float*          cbq  = cbs + (size_t)q * KCB * DIM;
        const unsigned short* cbbq = Cbb + (size_t)q * KCB * DIM;
        const float*          c2q  = c2 + (size_t)q * KCB;
        dim3 g(NBLK2, NTOK / 256);
        k_gemm_topk<<<g, 512, 0, stream>>>(Rb, cbbq, c2q, candS, candI);
        k_selupd<<<NTOK / 4, 256, 0, stream>>>(candS, candI, R, cbq, r2, c2q,
                                               idx_out, part + (size_t)q * (NTOK / 4),
                                               (ushort4*)Rb, (const float4*)x, q);
    }

    k_finalize_loss<<<1, 256, 0, stream>>>(part, loss_out);
}